// Round 9
// baseline (630.601 us; speedup 1.0000x reference)
//
#include <hip/hip_runtime.h>
#include <hip/hip_bf16.h>

#define INF 768
#define NSHORT 2000
#define NHEAD 2003
#define GRID 768   // 3 blocks/CU x 256 CUs; __launch_bounds__(256,3) guarantees co-residency

typedef __attribute__((ext_vector_type(8))) short  s16x8;
typedef __attribute__((ext_vector_type(4))) float  f32x4;
typedef __attribute__((ext_vector_type(8))) float  f32x8;

__device__ __forceinline__ float sigf(float z) { return 1.f / (1.f + __expf(-z)); }
__device__ __forceinline__ float softplusf(float z) {
    return fmaxf(z, 0.f) + __logf(1.f + __expf(-fabsf(z)));
}
__device__ __forceinline__ float qreduce16(float v) {
    v += __shfl_xor(v, 1); v += __shfl_xor(v, 2);
    v += __shfl_xor(v, 4); v += __shfl_xor(v, 8);
    return v;
}
__device__ __forceinline__ float wreduce64(float v) {
    v += __shfl_xor(v, 1);  v += __shfl_xor(v, 2);  v += __shfl_xor(v, 4);
    v += __shfl_xor(v, 8);  v += __shfl_xor(v, 16); v += __shfl_xor(v, 32);
    return v;
}
__device__ __forceinline__ short bfc(float x) {
    union { __hip_bfloat16 h; short s; } u; u.h = __float2bfloat16(x); return u.s;
}

// device-scope grid barrier: all GRID blocks co-resident (launch_bounds-guaranteed)
__device__ __forceinline__ void gsync(int* bar) {
    __syncthreads();
    if (threadIdx.x == 0) {
        __threadfence();                 // release: flush prior writes to device scope
        atomicAdd(bar, 1);               // device-scope by default
        while (__hip_atomic_load(bar, __ATOMIC_ACQUIRE, __HIP_MEMORY_SCOPE_AGENT) < GRID)
            __builtin_amdgcn_s_sleep(4);
        __threadfence();                 // acquire: invalidate local caches
    }
    __syncthreads();
}

// ---- chunked double-buffered staged MFMA GEMM (as R8, + entry barrier for LDS reuse) ----
template <int K32, int KC, int MODE, int AF32>
__device__ __forceinline__ void core_c(
    const void* __restrict__ Av, int kbase32,
    const float* __restrict__ W, int Kfull, int N, int stripe,
    short* __restrict__ lds,
    float* __restrict__ outH, int ldH,
    float* __restrict__ part, int pslot,
    const float* __restrict__ rootlogit, int ci)
{
    constexpr int NCH = K32 / KC;
    const int t = threadIdx.x;
    const int wave = t >> 6, lane = t & 63;
    const int quad = lane >> 4, l16 = lane & 15;
    const int rtb = wave * 4;

    const int sct = t >> 6, sl = t & 63;
    int scol = stripe * 64 + sct * 16 + (sl & 15);
    if (scol >= N) scol = N - 1;
    const float* wsrc = W + (size_t)scol * Kfull + kbase32 * 32 + (sl >> 4) * 8;

    size_t aoff[4];
#pragma unroll
    for (int rt = 0; rt < 4; rt++) {
        if (AF32)
            aoff[rt] = (size_t)((rtb + rt) * 16 + l16) * Kfull + kbase32 * 32 + quad * 8;
        else
            aoff[rt] = (size_t)(rtb + rt) * K32 * 512 + (size_t)lane * 8;
    }

    __syncthreads();  // previous stripe's LDS readers done (loop-reuse safety)

    // stage chunk 0
#pragma unroll
    for (int s = 0; s < KC; s++) {
        const f32x8 v = *(const f32x8*)(wsrc + (size_t)s * 32);
        s16x8 o;
#pragma unroll
        for (int i = 0; i < 8; i++) o[i] = bfc(v[i]);
        *(s16x8*)(lds + (((size_t)s * 4 + sct) * 64 + sl) * 8) = o;
    }
    __syncthreads();

    f32x4 acc[4][4];
#pragma unroll
    for (int rt = 0; rt < 4; rt++)
#pragma unroll
        for (int ct = 0; ct < 4; ct++) acc[rt][ct] = (f32x4){0.f, 0.f, 0.f, 0.f};

#pragma unroll
    for (int c = 0; c < NCH; c++) {
        short* lbuf = lds + (size_t)(c & 1) * (KC * 2048);
        f32x8 nv[KC];
        if (c + 1 < NCH) {
#pragma unroll
            for (int s = 0; s < KC; s++)
                nv[s] = *(const f32x8*)(wsrc + ((size_t)((c + 1) * KC + s)) * 32);
        }
#pragma unroll
        for (int jj = 0; jj < KC; jj++) {
            const int jg = c * KC + jj;
            s16x8 af[4];
            if (AF32) {
#pragma unroll
                for (int rt = 0; rt < 4; rt++) {
                    const f32x8 v = *(const f32x8*)((const float*)Av + aoff[rt] + (size_t)jg * 32);
#pragma unroll
                    for (int i = 0; i < 8; i++) af[rt][i] = bfc(v[i]);
                }
            } else {
#pragma unroll
                for (int rt = 0; rt < 4; rt++)
                    af[rt] = *(const s16x8*)((const short*)Av + aoff[rt] + (size_t)jg * 512);
            }
#pragma unroll
            for (int ct = 0; ct < 4; ct++) {
                const s16x8 wf = *(const s16x8*)(lbuf + (((size_t)jj * 4 + ct) * 64 + lane) * 8);
#pragma unroll
                for (int rt = 0; rt < 4; rt++)
                    acc[rt][ct] = __builtin_amdgcn_mfma_f32_16x16x32_bf16(
                        af[rt], wf, acc[rt][ct], 0, 0, 0);
            }
        }
        if (c + 1 < NCH) {
            short* nbuf = lds + (size_t)((c + 1) & 1) * (KC * 2048);
            __syncthreads();  // readers of nbuf's previous contents done
#pragma unroll
            for (int s = 0; s < KC; s++) {
                s16x8 o;
#pragma unroll
                for (int i = 0; i < 8; i++) o[i] = bfc(nv[s][i]);
                *(s16x8*)(nbuf + (((size_t)s * 4 + sct) * 64 + sl) * 8) = o;
            }
            __syncthreads();
        }
    }

    const int col0 = stripe * 64;
    if (MODE == 0) {
#pragma unroll
        for (int rt = 0; rt < 4; rt++)
#pragma unroll
            for (int ct = 0; ct < 4; ct++) {
                const int col = col0 + ct * 16 + l16;
                if (col < N) {
#pragma unroll
                    for (int r = 0; r < 4; r++)
                        outH[(size_t)((rtb + rt) * 16 + quad * 4 + r) * ldH + col] =
                            acc[rt][ct][r];
                }
            }
    } else {
        // sum_ct -log(1-r*sig(z)) = log prod(1+t) - log prod(1+t-r), t=e^-z
#pragma unroll
        for (int rt = 0; rt < 4; rt++) {
#pragma unroll
            for (int r = 0; r < 4; r++) {
                const int row = (rtb + rt) * 16 + quad * 4 + r;
                const float rv = sigf(rootlogit[row * 3 + ci]);
                float pd = 1.f, pn = 1.f;
#pragma unroll
                for (int ct = 0; ct < 4; ct++) {
                    const int col = col0 + ct * 16 + l16;
                    const float tv = fminf(__expf(-acc[rt][ct][r]), 1e6f);
                    const float d = (col < N) ? (1.f + tv) : 1.f;
                    const float n = (col < N) ? (1.f + tv - rv) : 1.f;
                    pd *= d; pn *= n;
                }
                float s = __logf(pd) - __logf(pn);
                s = qreduce16(s);
                if (l16 == 0) part[(size_t)pslot * 256 + row] = s;
            }
        }
    }
}

struct Params {
    const float *x, *headW, *w10, *w11, *w12, *w20, *w21, *w22;
    const float *g0, *g1, *g2, *b0, *b1, *b2;
    const int* target;
    float *zbase, *h0base, *h1base, *h2base;
    __hip_bfloat16 *f0, *f1, *f2, *p0, *p1, *p2;
    float *rootlogit, *phead, *part;
    int* bar;
    float* out;
};

__global__ __launch_bounds__(256, 3) void k_fused(Params P) {
    __shared__ __align__(16) short smem[8192];  // 16 KB, reused across phases
    const int bx = blockIdx.x, t = threadIdx.x;
    const int wave = t >> 6, lane = t & 63;

    // ---------------- phase 1: mm1 split-K GEMMs + roots + out init ----------------
    if (bx < 128) {
        const int stripe = bx >> 2, kq = bx & 3;
        core_c<6, 2, 0, 1>(P.x, kq * 6, P.headW, INF, NHEAD, stripe, smem,
                           P.zbase + (size_t)kq * 256 * 2048, 2048,
                           nullptr, 0, nullptr, 0);
    } else if (bx < 172) {
        const int m = bx - 128;
        if (m < 24) {
            const int stripe = m >> 2, kq = m & 3;
            core_c<6, 2, 0, 1>(P.x, kq * 6, P.w10, INF, 384, stripe, smem,
                               P.h0base + (size_t)kq * 256 * 384, 384,
                               nullptr, 0, nullptr, 0);
        } else if (m < 36) {
            const int m2 = m - 24, stripe = m2 >> 2, kq = m2 & 3;
            core_c<6, 2, 0, 1>(P.x, kq * 6, P.w11, INF, 192, stripe, smem,
                               P.h1base + (size_t)kq * 256 * 192, 192,
                               nullptr, 0, nullptr, 0);
        } else {
            const int m2 = m - 36, stripe = m2 >> 2, kq = m2 & 3;
            core_c<6, 2, 0, 1>(P.x, kq * 6, P.w12, INF, 96, stripe, smem,
                               P.h2base + (size_t)kq * 256 * 96, 96,
                               nullptr, 0, nullptr, 0);
        }
    } else if (bx < 428) {
        const int row = bx - 172;
        if (wave < 3) {   // exact fp32 root logits
            const float* xr = P.x + row * INF;
            const float* wr = P.headW + (size_t)(NSHORT + wave) * INF;
            float s = 0.f;
            for (int k = lane; k < INF; k += 64) s += xr[k] * wr[k];
            s = wreduce64(s);
            if (lane == 0) P.rootlogit[row * 3 + wave] = s;
        }
    } else if (bx == 700 && t == 0) {
        P.out[0] = 0.f;
    }

    gsync(P.bar + 0);

    // ---------------- phase 2: LayerNorm+ReLU + head softplus ----------------
    if (bx < 192) {
        const int task = bx * 4 + wave;  // 0..767
        const int ci = task >> 8, row = task & 255;
        const float *hb, *g, *bb; __hip_bfloat16 *fo, *po; int hsz, K32;
        if (ci == 0)      { hb = P.h0base; g = P.g0; bb = P.b0; fo = P.f0; po = P.p0; hsz = 384; K32 = 12; }
        else if (ci == 1) { hb = P.h1base; g = P.g1; bb = P.b1; fo = P.f1; po = P.p1; hsz = 192; K32 = 6; }
        else              { hb = P.h2base; g = P.g2; bb = P.b2; fo = P.f2; po = P.p2; hsz = 96;  K32 = 3; }
        const size_t qs = (size_t)256 * hsz;
        const float* hr = hb + (size_t)row * hsz;
        float s = 0.f, s2 = 0.f;
        for (int k = lane; k < hsz; k += 64) {
            const float v = hr[k] + hr[qs + k] + hr[2 * qs + k] + hr[3 * qs + k];
            s += v; s2 += v * v;
        }
        s = wreduce64(s); s2 = wreduce64(s2);
        const float mu = s / hsz;
        const float var = s2 / hsz - mu * mu;
        const float rsn = rsqrtf(var + 1e-5f);
        const int nch = hsz >> 3;
        if (lane < nch) {
            const f32x8 v0 = *(const f32x8*)(hr + lane * 8);
            const f32x8 v1 = *(const f32x8*)(hr + qs + lane * 8);
            const f32x8 v2 = *(const f32x8*)(hr + 2 * qs + lane * 8);
            const f32x8 v3 = *(const f32x8*)(hr + 3 * qs + lane * 8);
            const f32x8 gg = *(const f32x8*)(g + lane * 8);
            const f32x8 bv = *(const f32x8*)(bb + lane * 8);
            s16x8 o;
#pragma unroll
            for (int i = 0; i < 8; i++) {
                const float hv = v0[i] + v1[i] + v2[i] + v3[i];
                o[i] = bfc(fmaxf((hv - mu) * rsn * gg[i] + bv[i], 0.f));
            }
            *(s16x8*)((short*)fo + (size_t)row * hsz + lane * 8) = o;
            const size_t chunk = ((size_t)(row >> 4) * K32 + (lane >> 2)) * 64
                               + (lane & 3) * 16 + (row & 15);
            *(s16x8*)((short*)po + chunk * 8) = o;
        }
    } else if (bx < 448) {
        // head softplus row-sum: sum_{col<2000} softplus(sum_q z_q), grouped log
        const int row = bx - 192;
        float val = 0.f;
        if (t < 250) {
            const size_t base = (size_t)row * 2048 + t * 8;
            const f32x8 a = *(const f32x8*)(P.zbase + base);
            const f32x8 b = *(const f32x8*)(P.zbase + 524288 + base);
            const f32x8 c = *(const f32x8*)(P.zbase + 2 * 524288 + base);
            const f32x8 d = *(const f32x8*)(P.zbase + 3 * 524288 + base);
            float m = 0.f, Pp = 1.f;
#pragma unroll
            for (int i = 0; i < 8; i++) {
                const float z = a[i] + b[i] + c[i] + d[i];
                m += fmaxf(z, 0.f);
                Pp *= 1.f + __expf(-fabsf(z));
            }
            val = m + __logf(Pp);
        }
        val = wreduce64(val);
        float* red4 = (float*)smem;
        if (lane == 0) red4[wave] = val;
        __syncthreads();
        if (t == 0) P.phead[row] = red4[0] + red4[1] + red4[2] + red4[3];
    }

    gsync(P.bar + 1);

    // ---------------- phase 3: BCE dense partials (1533 stripes) ----------------
    for (int s = bx; s < 1533; s += GRID) {
        if (s < 157)
            core_c<12, 2, 2, 0>(P.p0, 0, P.w20, 384, 10000, s, smem,
                                nullptr, 0, P.part, s, P.rootlogit, 0);
        else if (s < 595)
            core_c<6, 2, 2, 0>(P.p1, 0, P.w21, 192, 28000, s - 157, smem,
                               nullptr, 0, P.part, s, P.rootlogit, 1);
        else
            core_c<3, 3, 2, 0>(P.p2, 0, P.w22, 96, 60000, s - 595, smem,
                               nullptr, 0, P.part, s, P.rootlogit, 2);
    }

    gsync(P.bar + 2);

    // ---------------- phase 4: per-row corrections + reduction + mean ----------------
    if (bx < 256) {
        const int row = bx;
        char* sm = (char*)smem;
        float* sx = (float*)sm;                                   // 768 f32
        __hip_bfloat16* shb = (__hip_bfloat16*)(sm + 3072);       // 672 bf16
        int* st = (int*)(sm + 4480);                              // 20 int
        float* scorr = (float*)(sm + 4608);                       // 4 f32
        float (*red)[4] = (float(*)[4])(sm + 4672);               // 3x4 f32
        for (int i = t; i < INF; i += 256) sx[i] = P.x[row * INF + i];
        for (int i = t; i < 384; i += 256) shb[i] = P.f0[row * 384 + i];
        for (int i = t; i < 192; i += 256) shb[384 + i] = P.f1[row * 192 + i];
        for (int i = t; i < 96; i += 256)  shb[576 + i] = P.f2[row * 96 + i];
        if (t < 20) st[t] = P.target[row * 20 + t];
        if (t < 4) scorr[t] = 0.f;
        __syncthreads();
        for (int l = wave; l < 20; l += 4) {
            const int tg = st[l];
            bool dup = false;
            for (int m = 0; m < l; m++) dup |= (st[m] == tg);
            if (dup) continue;
            if (tg < NSHORT) {
                const float* wr = P.headW + (size_t)tg * INF;
                float z = 0.f;
                for (int k = lane; k < INF; k += 64) z += sx[k] * wr[k];
                z = wreduce64(z);
                if (lane == 0) atomicAdd(&scorr[3], -z);
            } else {
                int ci, low, hsz, hoff; const float* w2;
                if (tg < 12000)      { ci = 0; low = 2000;  hsz = 384; hoff = 0;   w2 = P.w20; }
                else if (tg < 40000) { ci = 1; low = 12000; hsz = 192; hoff = 384; w2 = P.w21; }
                else                 { ci = 2; low = 40000; hsz = 96;  hoff = 576; w2 = P.w22; }
                const float* wr = w2 + (size_t)(tg - low) * hsz;
                float z = 0.f;
                for (int k = lane; k < hsz; k += 64)
                    z += __bfloat162float(shb[hoff + k]) * wr[k];
                z = wreduce64(z);
                if (lane == 0) {
                    const float rvv = sigf(P.rootlogit[row * 3 + ci]);
                    const float p = rvv * sigf(z);
                    atomicAdd(&scorr[ci],
                              -fmaxf(__logf(p), -100.f) + fmaxf(__logf(1.f - p), -100.f));
                }
            }
        }
        float c0 = 0.f, c1 = 0.f, c2 = 0.f;
        for (int i = t; i < 1533; i += 256) {
            const float v = P.part[(size_t)i * 256 + row];
            if (i < 157) c0 += v; else if (i < 595) c1 += v; else c2 += v;
        }
        c0 = wreduce64(c0); c1 = wreduce64(c1); c2 = wreduce64(c2);
        if (lane == 0) { red[0][wave] = c0; red[1][wave] = c1; red[2][wave] = c2; }
        __syncthreads();
        if (t == 0) {
            float cc[3];
            for (int i = 0; i < 3; i++) cc[i] = red[i][0] + red[i][1] + red[i][2] + red[i][3];
            float hsum = P.phead[row] + scorr[3];
            bool act[3] = {false, false, false};
            for (int l = 0; l < 20; l++) {
                const int tg = P.target[row * 20 + l];
                if (tg >= 2000) {
                    if (tg < 12000) act[0] = true;
                    else if (tg < 40000) act[1] = true;
                    else act[2] = true;
                }
            }
            float total = 0.f, num = 2000.f;
            const float csz[3] = {10000.f, 28000.f, 60000.f};
            for (int i = 0; i < 3; i++) {
                if (act[i]) { total += cc[i] + scorr[i]; num += csz[i]; }
                else        { hsum += softplusf(P.rootlogit[row * 3 + i]); num += 1.f; }
            }
            atomicAdd(P.out, (hsum + total) / num * (1.f / 256.f));
        }
    }
}

extern "C" void kernel_launch(void* const* d_in, const int* in_sizes, int n_in,
                              void* d_out, int out_size, void* d_ws, size_t ws_size,
                              hipStream_t stream) {
    Params P;
    P.x      = (const float*)d_in[0];
    P.headW  = (const float*)d_in[1];
    P.target = (const int*)d_in[2];
    P.w10 = (const float*)d_in[3];
    P.g0  = (const float*)d_in[4];
    P.b0  = (const float*)d_in[5];
    P.w20 = (const float*)d_in[6];
    P.w11 = (const float*)d_in[7];
    P.g1  = (const float*)d_in[8];
    P.b1  = (const float*)d_in[9];
    P.w21 = (const float*)d_in[10];
    P.w12 = (const float*)d_in[11];
    P.g2  = (const float*)d_in[12];
    P.b2  = (const float*)d_in[13];
    P.w22 = (const float*)d_in[14];
    P.out = (float*)d_out;

    char* ws = (char*)d_ws;
    size_t off = 0;
    auto carve = [&](size_t bytes) -> void* {
        void* p = ws + off;
        off += (bytes + 255) & ~(size_t)255;
        return p;
    };
    P.zbase     = (float*)carve((size_t)4 * 256 * 2048 * 4);
    P.h0base    = (float*)carve((size_t)4 * 256 * 384 * 4);
    P.h1base    = (float*)carve((size_t)4 * 256 * 192 * 4);
    P.h2base    = (float*)carve((size_t)4 * 256 * 96 * 4);
    P.f0        = (__hip_bfloat16*)carve((size_t)256 * 384 * 2);
    P.f1        = (__hip_bfloat16*)carve((size_t)256 * 192 * 2);
    P.f2        = (__hip_bfloat16*)carve((size_t)256 * 96 * 2);
    P.p0        = (__hip_bfloat16*)carve((size_t)256 * 384 * 2);
    P.p1        = (__hip_bfloat16*)carve((size_t)256 * 192 * 2);
    P.p2        = (__hip_bfloat16*)carve((size_t)256 * 96 * 2);
    P.rootlogit = (float*)carve((size_t)256 * 3 * 4);
    P.phead     = (float*)carve((size_t)256 * 4);
    P.part      = (float*)carve((size_t)1536 * 256 * 4);
    P.bar       = (int*)carve(256);

    hipMemsetAsync(P.bar, 0, 3 * sizeof(int), stream);
    k_fused<<<GRID, 256, 0, stream>>>(P);

    (void)in_sizes; (void)n_in; (void)out_size; (void)ws_size;
}

// Round 10
// 219.945 us; speedup vs baseline: 2.8671x; 2.8671x over previous
//
#include <hip/hip_runtime.h>
#include <hip/hip_bf16.h>

#define INF 768
#define NSHORT 2000
#define NHEAD 2003

typedef __attribute__((ext_vector_type(8))) short  s16x8;
typedef __attribute__((ext_vector_type(4))) float  f32x4;
typedef __attribute__((ext_vector_type(8))) float  f32x8;

__device__ __forceinline__ float sigf(float z) { return 1.f / (1.f + __expf(-z)); }
__device__ __forceinline__ float softplusf(float z) {
    return fmaxf(z, 0.f) + __logf(1.f + __expf(-fabsf(z)));
}
__device__ __forceinline__ float qreduce16(float v) {
    v += __shfl_xor(v, 1); v += __shfl_xor(v, 2);
    v += __shfl_xor(v, 4); v += __shfl_xor(v, 8);
    return v;
}
__device__ __forceinline__ float wreduce64(float v) {
    v += __shfl_xor(v, 1);  v += __shfl_xor(v, 2);  v += __shfl_xor(v, 4);
    v += __shfl_xor(v, 8);  v += __shfl_xor(v, 16); v += __shfl_xor(v, 32);
    return v;
}
__device__ __forceinline__ short bfc(float x) {
    union { __hip_bfloat16 h; short s; } u; u.h = __float2bfloat16(x); return u.s;
}

// ---- chunked double-buffered staged MFMA GEMM (R8 core, + MODE 1) ----
// Block = 256 rows x 64-col stripe, 4 waves x 64 rows; K in NCH=K32/KC chunks.
// MODE 0: store z. MODE 1: grouped-log softplus rowsum (col<NSHORT) -> part[pslot*256+row].
// MODE 2: grouped-log BCE rowsum -> part[pslot*256+row].
template <int K32, int KC, int MODE, int AF32>
__device__ __forceinline__ void core_c(
    const void* __restrict__ Av, int kbase32,
    const float* __restrict__ W, int Kfull, int N, int stripe,
    short* __restrict__ lds,
    float* __restrict__ outH, int ldH,
    float* __restrict__ part, int pslot,
    const float* __restrict__ rootlogit, int ci)
{
    constexpr int NCH = K32 / KC;
    const int t = threadIdx.x;
    const int wave = t >> 6, lane = t & 63;
    const int quad = lane >> 4, l16 = lane & 15;
    const int rtb = wave * 4;

    const int sct = t >> 6, sl = t & 63;
    int scol = stripe * 64 + sct * 16 + (sl & 15);
    if (scol >= N) scol = N - 1;
    const float* wsrc = W + (size_t)scol * Kfull + kbase32 * 32 + (sl >> 4) * 8;

    size_t aoff[4];
#pragma unroll
    for (int rt = 0; rt < 4; rt++) {
        if (AF32)
            aoff[rt] = (size_t)((rtb + rt) * 16 + l16) * Kfull + kbase32 * 32 + quad * 8;
        else
            aoff[rt] = (size_t)(rtb + rt) * K32 * 512 + (size_t)lane * 8;
    }

    // stage chunk 0
#pragma unroll
    for (int s = 0; s < KC; s++) {
        const f32x8 v = *(const f32x8*)(wsrc + (size_t)s * 32);
        s16x8 o;
#pragma unroll
        for (int i = 0; i < 8; i++) o[i] = bfc(v[i]);
        *(s16x8*)(lds + (((size_t)s * 4 + sct) * 64 + sl) * 8) = o;
    }
    __syncthreads();

    f32x4 acc[4][4];
#pragma unroll
    for (int rt = 0; rt < 4; rt++)
#pragma unroll
        for (int ct = 0; ct < 4; ct++) acc[rt][ct] = (f32x4){0.f, 0.f, 0.f, 0.f};

#pragma unroll
    for (int c = 0; c < NCH; c++) {
        short* lbuf = lds + (size_t)(c & 1) * (KC * 2048);
        f32x8 nv[KC];
        if (c + 1 < NCH) {
#pragma unroll
            for (int s = 0; s < KC; s++)
                nv[s] = *(const f32x8*)(wsrc + ((size_t)((c + 1) * KC + s)) * 32);
        }
#pragma unroll
        for (int jj = 0; jj < KC; jj++) {
            const int jg = c * KC + jj;
            s16x8 af[4];
            if (AF32) {
#pragma unroll
                for (int rt = 0; rt < 4; rt++) {
                    const f32x8 v = *(const f32x8*)((const float*)Av + aoff[rt] + (size_t)jg * 32);
#pragma unroll
                    for (int i = 0; i < 8; i++) af[rt][i] = bfc(v[i]);
                }
            } else {
#pragma unroll
                for (int rt = 0; rt < 4; rt++)
                    af[rt] = *(const s16x8*)((const short*)Av + aoff[rt] + (size_t)jg * 512);
            }
#pragma unroll
            for (int ct = 0; ct < 4; ct++) {
                const s16x8 wf = *(const s16x8*)(lbuf + (((size_t)jj * 4 + ct) * 64 + lane) * 8);
#pragma unroll
                for (int rt = 0; rt < 4; rt++)
                    acc[rt][ct] = __builtin_amdgcn_mfma_f32_16x16x32_bf16(
                        af[rt], wf, acc[rt][ct], 0, 0, 0);
            }
        }
        if (c + 1 < NCH) {
            short* nbuf = lds + (size_t)((c + 1) & 1) * (KC * 2048);
            __syncthreads();
#pragma unroll
            for (int s = 0; s < KC; s++) {
                s16x8 o;
#pragma unroll
                for (int i = 0; i < 8; i++) o[i] = bfc(nv[s][i]);
                *(s16x8*)(nbuf + (((size_t)s * 4 + sct) * 64 + sl) * 8) = o;
            }
            __syncthreads();
        }
    }

    const int col0 = stripe * 64;
    if (MODE == 0) {
#pragma unroll
        for (int rt = 0; rt < 4; rt++)
#pragma unroll
            for (int ct = 0; ct < 4; ct++) {
                const int col = col0 + ct * 16 + l16;
                if (col < N) {
#pragma unroll
                    for (int r = 0; r < 4; r++)
                        outH[(size_t)((rtb + rt) * 16 + quad * 4 + r) * ldH + col] =
                            acc[rt][ct][r];
                }
            }
    } else if (MODE == 1) {
        // softplus rowsum, grouped log: sum max(z,0) + log prod(1+e^-|z|)
#pragma unroll
        for (int rt = 0; rt < 4; rt++) {
#pragma unroll
            for (int r = 0; r < 4; r++) {
                const int row = (rtb + rt) * 16 + quad * 4 + r;
                float m = 0.f, Pp = 1.f;
#pragma unroll
                for (int ct = 0; ct < 4; ct++) {
                    const int col = col0 + ct * 16 + l16;
                    if (col < NSHORT) {
                        const float z = acc[rt][ct][r];
                        m += fmaxf(z, 0.f);
                        Pp *= 1.f + __expf(-fabsf(z));
                    }
                }
                float s = m + __logf(Pp);
                s = qreduce16(s);
                if (l16 == 0) part[(size_t)pslot * 256 + row] = s;
            }
        }
    } else {
#pragma unroll
        for (int rt = 0; rt < 4; rt++) {
#pragma unroll
            for (int r = 0; r < 4; r++) {
                const int row = (rtb + rt) * 16 + quad * 4 + r;
                const float rv = sigf(rootlogit[row * 3 + ci]);
                float pd = 1.f, pn = 1.f;
#pragma unroll
                for (int ct = 0; ct < 4; ct++) {
                    const int col = col0 + ct * 16 + l16;
                    const float tv = fminf(__expf(-acc[rt][ct][r]), 1e6f);
                    const float d = (col < N) ? (1.f + tv) : 1.f;
                    const float n = (col < N) ? (1.f + tv - rv) : 1.f;
                    pd *= d; pn *= n;
                }
                float s = __logf(pd) - __logf(pn);
                s = qreduce16(s);
                if (l16 == 0) part[(size_t)pslot * 256 + row] = s;
            }
        }
    }
}

// ---- single-stage one-barrier MFMA GEMM for BCE (A = fragment-linear bf16) ----
// Whole 64-col x K stripe staged fp32->bf16 into LDS in one burst (ping-pong groups),
// ONE barrier, then pure MFMA + grouped-log epilogue.
template <int K32>
__device__ __forceinline__ void core_b(
    const __hip_bfloat16* __restrict__ Ap,
    const float* __restrict__ W, int N, int stripe,
    short* __restrict__ lds,
    float* __restrict__ part, int pslot,
    const float* __restrict__ rootlogit, int ci)
{
    const int t = threadIdx.x;
    const int wave = t >> 6, lane = t & 63;
    const int quad = lane >> 4, l16 = lane & 15;
    const int rtb = wave * 4;
    const int Kfull = K32 * 32;

    // staging: thread t owns col (fixed), walks k; position p -> LDS chunk p*2048+...
    const int sct = t >> 6, sl = t & 63;
    int scol = stripe * 64 + sct * 16 + (sl & 15);
    if (scol >= N) scol = N - 1;
    const float* wsrc = W + (size_t)scol * Kfull + (sl >> 4) * 8;
    short* wdst = lds + ((size_t)sct * 64 + sl) * 8;

    constexpr int G = (K32 <= 6) ? K32 : 6;
    constexpr int NG = K32 / G;
    f32x8 buf[G];
#pragma unroll
    for (int s = 0; s < G; s++) buf[s] = *(const f32x8*)(wsrc + (size_t)s * 32);
#pragma unroll
    for (int gg = 0; gg < NG; gg++) {
        f32x8 nbuf[G];
        if (gg + 1 < NG) {
#pragma unroll
            for (int s = 0; s < G; s++)
                nbuf[s] = *(const f32x8*)(wsrc + (size_t)((gg + 1) * G + s) * 32);
        }
#pragma unroll
        for (int s = 0; s < G; s++) {
            s16x8 o;
#pragma unroll
            for (int i = 0; i < 8; i++) o[i] = bfc(buf[s][i]);
            *(s16x8*)(wdst + (size_t)(gg * G + s) * 2048) = o;
        }
        if (gg + 1 < NG) {
#pragma unroll
            for (int s = 0; s < G; s++) buf[s] = nbuf[s];
        }
    }
    __syncthreads();   // the ONLY barrier

    const short* abase = (const short*)Ap + (size_t)lane * 8;
    f32x4 acc[4][4];
#pragma unroll
    for (int rt = 0; rt < 4; rt++)
#pragma unroll
        for (int ct = 0; ct < 4; ct++) acc[rt][ct] = (f32x4){0.f, 0.f, 0.f, 0.f};

#pragma unroll
    for (int j = 0; j < K32; j++) {
        s16x8 af[4];
#pragma unroll
        for (int rt = 0; rt < 4; rt++)
            af[rt] = *(const s16x8*)(abase + (size_t)((rtb + rt) * K32 + j) * 512);
#pragma unroll
        for (int ct = 0; ct < 4; ct++) {
            const s16x8 wf = *(const s16x8*)(lds + (((size_t)j * 4 + ct) * 64 + lane) * 8);
#pragma unroll
            for (int rt = 0; rt < 4; rt++)
                acc[rt][ct] = __builtin_amdgcn_mfma_f32_16x16x32_bf16(
                    af[rt], wf, acc[rt][ct], 0, 0, 0);
        }
    }

    const int col0 = stripe * 64;
#pragma unroll
    for (int rt = 0; rt < 4; rt++) {
#pragma unroll
        for (int r = 0; r < 4; r++) {
            const int row = (rtb + rt) * 16 + quad * 4 + r;
            const float rv = sigf(rootlogit[row * 3 + ci]);
            float pd = 1.f, pn = 1.f;
#pragma unroll
            for (int ct = 0; ct < 4; ct++) {
                const int col = col0 + ct * 16 + l16;
                const float tv = fminf(__expf(-acc[rt][ct][r]), 1e6f);
                const float d = (col < N) ? (1.f + tv) : 1.f;
                const float n = (col < N) ? (1.f + tv - rv) : 1.f;
                pd *= d; pn *= n;
            }
            float s = __logf(pd) - __logf(pn);
            s = qreduce16(s);
            if (l16 == 0) part[(size_t)pslot * 256 + row] = s;
        }
    }
}

// head softplus (32, full-K) + w1 h (11, full-K) + roots (256) = 299 blocks
__global__ __launch_bounds__(256) void k_mm1(
    const float* __restrict__ x, const float* __restrict__ headW,
    const float* __restrict__ w10, const float* __restrict__ w11,
    const float* __restrict__ w12,
    float* __restrict__ phead,     // [32][256]
    float* h0, float* h1, float* h2,
    float* __restrict__ rootlogit)
{
    __shared__ __align__(16) short smem[16384];  // 32 KB: 2 x KC=4 chunks
    const int bx = blockIdx.x;
    if (bx < 32) {
        core_c<24, 4, 1, 1>(x, 0, headW, INF, NHEAD, bx, smem,
                            nullptr, 0, phead, bx, nullptr, 0);
    } else if (bx < 38) {
        core_c<24, 4, 0, 1>(x, 0, w10, INF, 384, bx - 32, smem,
                            h0, 384, nullptr, 0, nullptr, 0);
    } else if (bx < 41) {
        core_c<24, 4, 0, 1>(x, 0, w11, INF, 192, bx - 38, smem,
                            h1, 192, nullptr, 0, nullptr, 0);
    } else if (bx < 43) {
        core_c<24, 4, 0, 1>(x, 0, w12, INF, 96, bx - 41, smem,
                            h2, 96, nullptr, 0, nullptr, 0);
    } else {
        const int row = bx - 43, wave = threadIdx.x >> 6, lane = threadIdx.x & 63;
        if (wave < 3) {   // exact fp32 root logits
            const float* xr = x + row * INF;
            const float* wr = headW + (size_t)(NSHORT + wave) * INF;
            float s = 0.f;
            for (int k = lane; k < INF; k += 64) s += xr[k] * wr[k];
            s = wreduce64(s);
            if (lane == 0) rootlogit[row * 3 + wave] = s;
        }
    }
}

// LayerNorm+ReLU -> bf16 flat (f*) + fragment-permuted (p*); also zeroes out[0]
__global__ __launch_bounds__(256) void k_ln(const float* h0, const float* h1, const float* h2,
                                            const float* g0, const float* g1, const float* g2,
                                            const float* b0, const float* b1, const float* b2,
                                            __hip_bfloat16* f0, __hip_bfloat16* f1,
                                            __hip_bfloat16* f2,
                                            __hip_bfloat16* p0, __hip_bfloat16* p1,
                                            __hip_bfloat16* p2,
                                            float* __restrict__ out) {
    if (blockIdx.x == 0 && threadIdx.x == 0) out[0] = 0.f;
    const int task = blockIdx.x * 4 + (threadIdx.x >> 6);  // 0..767
    const int ci = task >> 8, row = task & 255, lane = threadIdx.x & 63;
    const float *h, *g, *bb; __hip_bfloat16 *fo, *po; int hsz, K32;
    if (ci == 0)      { h = h0; g = g0; bb = b0; fo = f0; po = p0; hsz = 384; K32 = 12; }
    else if (ci == 1) { h = h1; g = g1; bb = b1; fo = f1; po = p1; hsz = 192; K32 = 6; }
    else              { h = h2; g = g2; bb = b2; fo = f2; po = p2; hsz = 96;  K32 = 3; }
    const float* hr = h + (size_t)row * hsz;
    float s = 0.f, s2 = 0.f;
    for (int k = lane; k < hsz; k += 64) { const float v = hr[k]; s += v; s2 += v * v; }
    s = wreduce64(s); s2 = wreduce64(s2);
    const float mu = s / hsz;
    const float var = s2 / hsz - mu * mu;
    const float rsn = rsqrtf(var + 1e-5f);
    const int nch = hsz >> 3;
    if (lane < nch) {
        const f32x8 v = *(const f32x8*)(hr + lane * 8);
        const f32x8 gg = *(const f32x8*)(g + lane * 8);
        const f32x8 bv = *(const f32x8*)(bb + lane * 8);
        s16x8 o;
#pragma unroll
        for (int i = 0; i < 8; i++)
            o[i] = bfc(fmaxf((v[i] - mu) * rsn * gg[i] + bv[i], 0.f));
        *(s16x8*)((short*)fo + (size_t)row * hsz + lane * 8) = o;
        const size_t chunk = ((size_t)(row >> 4) * K32 + (lane >> 2)) * 64
                           + (lane & 3) * 16 + (row & 15);
        *(s16x8*)((short*)po + chunk * 8) = o;
    }
}

// BCE dense partials: 1533 stripes, single-stage one-barrier core
__global__ __launch_bounds__(256) void k_bce(const __hip_bfloat16* p0,
                                             const __hip_bfloat16* p1,
                                             const __hip_bfloat16* p2,
                                             const float* __restrict__ w20,
                                             const float* __restrict__ w21,
                                             const float* __restrict__ w22,
                                             float* __restrict__ part,
                                             const float* __restrict__ rootlogit) {
    __shared__ __align__(16) short smem[24576];  // 48 KB (c0: 12 chunks x 4 KB)
    const int s = blockIdx.x;
    if (s < 157)
        core_b<12>(p0, w20, 10000, s, smem, part, s, rootlogit, 0);
    else if (s < 595)
        core_b<6>(p1, w21, 28000, s - 157, smem, part, s, rootlogit, 1);
    else
        core_b<3>(p2, w22, 60000, s - 595, smem, part, s, rootlogit, 2);
}

// per-row: target corrections + partial reduction + final mean
__global__ __launch_bounds__(256) void k_red(const float* __restrict__ part,
                                             const float* __restrict__ phead,
                                             const float* __restrict__ rootlogit,
                                             const int* __restrict__ target,
                                             const float* __restrict__ x,
                                             const float* __restrict__ headW,
                                             const __hip_bfloat16* f0,
                                             const __hip_bfloat16* f1,
                                             const __hip_bfloat16* f2,
                                             const float* w20, const float* w21, const float* w22,
                                             float* __restrict__ out) {
    const int row = blockIdx.x;
    const int t = threadIdx.x, wave = t >> 6, lane = t & 63;
    __shared__ float sx[INF];
    __shared__ __hip_bfloat16 shb[384 + 192 + 96];
    __shared__ int st[20];
    __shared__ float scorr[4];
    __shared__ float red[4][4];
    for (int i = t; i < INF; i += 256) sx[i] = x[row * INF + i];
    for (int i = t; i < 384; i += 256) shb[i] = f0[row * 384 + i];
    for (int i = t; i < 192; i += 256) shb[384 + i] = f1[row * 192 + i];
    for (int i = t; i < 96; i += 256)  shb[576 + i] = f2[row * 96 + i];
    if (t < 20) st[t] = target[row * 20 + t];
    if (t < 4) scorr[t] = 0.f;
    __syncthreads();
    for (int l = wave; l < 20; l += 4) {
        const int tg = st[l];
        bool dup = false;
        for (int m = 0; m < l; m++) dup |= (st[m] == tg);
        if (dup) continue;
        if (tg < NSHORT) {
            const float* wr = headW + (size_t)tg * INF;
            float z = 0.f;
            for (int k = lane; k < INF; k += 64) z += sx[k] * wr[k];
            z = wreduce64(z);
            if (lane == 0) atomicAdd(&scorr[3], -z);
        } else {
            int ci, low, hsz, hoff; const float* w2;
            if (tg < 12000)      { ci = 0; low = 2000;  hsz = 384; hoff = 0;   w2 = w20; }
            else if (tg < 40000) { ci = 1; low = 12000; hsz = 192; hoff = 384; w2 = w21; }
            else                 { ci = 2; low = 40000; hsz = 96;  hoff = 576; w2 = w22; }
            const float* wr = w2 + (size_t)(tg - low) * hsz;
            float z = 0.f;
            for (int k = lane; k < hsz; k += 64)
                z += __bfloat162float(shb[hoff + k]) * wr[k];
            z = wreduce64(z);
            if (lane == 0) {
                const float rvv = sigf(rootlogit[row * 3 + ci]);
                const float p = rvv * sigf(z);
                atomicAdd(&scorr[ci],
                          -fmaxf(__logf(p), -100.f) + fmaxf(__logf(1.f - p), -100.f));
            }
        }
    }
    // dense-partial + head-partial reduction
    float c0 = 0.f, c1 = 0.f, c2 = 0.f, hs = 0.f;
    for (int i = t; i < 1533; i += 256) {
        const float v = part[(size_t)i * 256 + row];
        if (i < 157) c0 += v; else if (i < 595) c1 += v; else c2 += v;
    }
    if (t < 32) hs = phead[(size_t)t * 256 + row];
    c0 = wreduce64(c0); c1 = wreduce64(c1); c2 = wreduce64(c2); hs = wreduce64(hs);
    if (lane == 0) { red[0][wave] = c0; red[1][wave] = c1; red[2][wave] = c2; red[3][wave] = hs; }
    __syncthreads();
    if (t == 0) {
        float cc[3];
        for (int i = 0; i < 3; i++) cc[i] = red[i][0] + red[i][1] + red[i][2] + red[i][3];
        float hsum = red[3][0] + red[3][1] + red[3][2] + red[3][3] + scorr[3];
        bool act[3] = {false, false, false};
        for (int l = 0; l < 20; l++) {
            const int tg = target[row * 20 + l];
            if (tg >= 2000) {
                if (tg < 12000) act[0] = true;
                else if (tg < 40000) act[1] = true;
                else act[2] = true;
            }
        }
        float total = 0.f, num = 2000.f;
        const float csz[3] = {10000.f, 28000.f, 60000.f};
        for (int i = 0; i < 3; i++) {
            if (act[i]) { total += cc[i] + scorr[i]; num += csz[i]; }
            else        { hsum += softplusf(rootlogit[row * 3 + i]); num += 1.f; }
        }
        atomicAdd(out, (hsum + total) / num * (1.f / 256.f));
    }
}

extern "C" void kernel_launch(void* const* d_in, const int* in_sizes, int n_in,
                              void* d_out, int out_size, void* d_ws, size_t ws_size,
                              hipStream_t stream) {
    const float* x      = (const float*)d_in[0];
    const float* headW  = (const float*)d_in[1];
    const int*   target = (const int*)d_in[2];
    const float* w10 = (const float*)d_in[3];
    const float* g0  = (const float*)d_in[4];
    const float* b0  = (const float*)d_in[5];
    const float* w20 = (const float*)d_in[6];
    const float* w11 = (const float*)d_in[7];
    const float* g1  = (const float*)d_in[8];
    const float* b1  = (const float*)d_in[9];
    const float* w21 = (const float*)d_in[10];
    const float* w12 = (const float*)d_in[11];
    const float* g2  = (const float*)d_in[12];
    const float* b2  = (const float*)d_in[13];
    const float* w22 = (const float*)d_in[14];
    float* out = (float*)d_out;

    char* ws = (char*)d_ws;
    size_t off = 0;
    auto carve = [&](size_t bytes) -> void* {
        void* p = ws + off;
        off += (bytes + 255) & ~(size_t)255;
        return p;
    };
    float* h0            = (float*)carve((size_t)256 * 384 * 4);
    float* h1            = (float*)carve((size_t)256 * 192 * 4);
    float* h2            = (float*)carve((size_t)256 * 96 * 4);
    __hip_bfloat16* f0   = (__hip_bfloat16*)carve((size_t)256 * 384 * 2);
    __hip_bfloat16* f1   = (__hip_bfloat16*)carve((size_t)256 * 192 * 2);
    __hip_bfloat16* f2   = (__hip_bfloat16*)carve((size_t)256 * 96 * 2);
    __hip_bfloat16* p0   = (__hip_bfloat16*)carve((size_t)256 * 384 * 2);
    __hip_bfloat16* p1   = (__hip_bfloat16*)carve((size_t)256 * 192 * 2);
    __hip_bfloat16* p2   = (__hip_bfloat16*)carve((size_t)256 * 96 * 2);
    float* rootlogit     = (float*)carve((size_t)256 * 3 * 4);
    float* phead         = (float*)carve((size_t)32 * 256 * 4);
    float* part          = (float*)carve((size_t)1536 * 256 * 4);

    k_mm1<<<299, 256, 0, stream>>>(x, headW, w10, w11, w12,
                                   phead, h0, h1, h2, rootlogit);
    k_ln<<<192, 256, 0, stream>>>(h0, h1, h2, g0, g1, g2, b0, b1, b2,
                                  f0, f1, f2, p0, p1, p2, out);
    k_bce<<<1533, 256, 0, stream>>>(p0, p1, p2, w20, w21, w22, part, rootlogit);
    k_red<<<256, 256, 0, stream>>>(part, phead, rootlogit, target, x, headW,
                                   f0, f1, f2, w20, w21, w22, out);

    (void)in_sizes; (void)n_in; (void)out_size; (void)ws_size;
}

// Round 11
// 207.071 us; speedup vs baseline: 3.0453x; 1.0622x over previous
//
#include <hip/hip_runtime.h>
#include <hip/hip_bf16.h>

#define INF 768
#define NSHORT 2000
#define NHEAD 2003

typedef __attribute__((ext_vector_type(8))) short  s16x8;
typedef __attribute__((ext_vector_type(4))) float  f32x4;
typedef __attribute__((ext_vector_type(8))) float  f32x8;

__device__ __forceinline__ float sigf(float z) { return 1.f / (1.f + __expf(-z)); }
__device__ __forceinline__ float softplusf(float z) {
    return fmaxf(z, 0.f) + __logf(1.f + __expf(-fabsf(z)));
}
__device__ __forceinline__ float qreduce16(float v) {
    v += __shfl_xor(v, 1); v += __shfl_xor(v, 2);
    v += __shfl_xor(v, 4); v += __shfl_xor(v, 8);
    return v;
}
__device__ __forceinline__ float wreduce64(float v) {
    v += __shfl_xor(v, 1);  v += __shfl_xor(v, 2);  v += __shfl_xor(v, 4);
    v += __shfl_xor(v, 8);  v += __shfl_xor(v, 16); v += __shfl_xor(v, 32);
    return v;
}
__device__ __forceinline__ short bfc(float x) {
    union { __hip_bfloat16 h; short s; } u; u.h = __float2bfloat16(x); return u.s;
}

// ---- chunked double-buffered staged MFMA GEMM ----
// Block = 256 rows x 64-col stripe, 4 waves x 64 rows; K in NCH=K32/KC chunks.
// Per chunk: issue next chunk's W loads -> MFMA current (LDS) -> cvt+write next -> barrier.
// MODE 0: store z. MODE 1: grouped-log softplus rowsum (col<NSHORT) -> part[pslot*256+row].
// MODE 2: grouped-log BCE rowsum -> part[pslot*256+row].
template <int K32, int KC, int MODE, int AF32>
__device__ __forceinline__ void core_c(
    const void* __restrict__ Av, int kbase32,
    const float* __restrict__ W, int Kfull, int N, int stripe,
    short* __restrict__ lds,
    float* __restrict__ outH, int ldH,
    float* __restrict__ part, int pslot,
    const float* __restrict__ rootlogit, int ci)
{
    constexpr int NCH = K32 / KC;
    const int t = threadIdx.x;
    const int wave = t >> 6, lane = t & 63;
    const int quad = lane >> 4, l16 = lane & 15;
    const int rtb = wave * 4;

    const int sct = t >> 6, sl = t & 63;
    int scol = stripe * 64 + sct * 16 + (sl & 15);
    if (scol >= N) scol = N - 1;
    const float* wsrc = W + (size_t)scol * Kfull + kbase32 * 32 + (sl >> 4) * 8;

    size_t aoff[4];
#pragma unroll
    for (int rt = 0; rt < 4; rt++) {
        if (AF32)
            aoff[rt] = (size_t)((rtb + rt) * 16 + l16) * Kfull + kbase32 * 32 + quad * 8;
        else
            aoff[rt] = (size_t)(rtb + rt) * K32 * 512 + (size_t)lane * 8;
    }

    // stage chunk 0
#pragma unroll
    for (int s = 0; s < KC; s++) {
        const f32x8 v = *(const f32x8*)(wsrc + (size_t)s * 32);
        s16x8 o;
#pragma unroll
        for (int i = 0; i < 8; i++) o[i] = bfc(v[i]);
        *(s16x8*)(lds + (((size_t)s * 4 + sct) * 64 + sl) * 8) = o;
    }
    __syncthreads();

    f32x4 acc[4][4];
#pragma unroll
    for (int rt = 0; rt < 4; rt++)
#pragma unroll
        for (int ct = 0; ct < 4; ct++) acc[rt][ct] = (f32x4){0.f, 0.f, 0.f, 0.f};

#pragma unroll
    for (int c = 0; c < NCH; c++) {
        short* lbuf = lds + (size_t)(c & 1) * (KC * 2048);
        f32x8 nv[KC];
        if (c + 1 < NCH) {   // issue next-chunk loads; they fly during MFMA below
#pragma unroll
            for (int s = 0; s < KC; s++)
                nv[s] = *(const f32x8*)(wsrc + ((size_t)((c + 1) * KC + s)) * 32);
        }
#pragma unroll
        for (int jj = 0; jj < KC; jj++) {
            const int jg = c * KC + jj;
            s16x8 af[4];
            if (AF32) {
#pragma unroll
                for (int rt = 0; rt < 4; rt++) {
                    const f32x8 v = *(const f32x8*)((const float*)Av + aoff[rt] + (size_t)jg * 32);
#pragma unroll
                    for (int i = 0; i < 8; i++) af[rt][i] = bfc(v[i]);
                }
            } else {
#pragma unroll
                for (int rt = 0; rt < 4; rt++)
                    af[rt] = *(const s16x8*)((const short*)Av + aoff[rt] + (size_t)jg * 512);
            }
#pragma unroll
            for (int ct = 0; ct < 4; ct++) {
                const s16x8 wf = *(const s16x8*)(lbuf + (((size_t)jj * 4 + ct) * 64 + lane) * 8);
#pragma unroll
                for (int rt = 0; rt < 4; rt++)
                    acc[rt][ct] = __builtin_amdgcn_mfma_f32_16x16x32_bf16(
                        af[rt], wf, acc[rt][ct], 0, 0, 0);
            }
        }
        if (c + 1 < NCH) {
            short* nbuf = lds + (size_t)((c + 1) & 1) * (KC * 2048);
            __syncthreads();  // readers of nbuf's previous contents done
#pragma unroll
            for (int s = 0; s < KC; s++) {
                s16x8 o;
#pragma unroll
                for (int i = 0; i < 8; i++) o[i] = bfc(nv[s][i]);
                *(s16x8*)(nbuf + (((size_t)s * 4 + sct) * 64 + sl) * 8) = o;
            }
            __syncthreads();
        }
    }

    const int col0 = stripe * 64;
    if (MODE == 0) {
#pragma unroll
        for (int rt = 0; rt < 4; rt++)
#pragma unroll
            for (int ct = 0; ct < 4; ct++) {
                const int col = col0 + ct * 16 + l16;
                if (col < N) {
#pragma unroll
                    for (int r = 0; r < 4; r++)
                        outH[(size_t)((rtb + rt) * 16 + quad * 4 + r) * ldH + col] =
                            acc[rt][ct][r];
                }
            }
    } else if (MODE == 1) {
        // softplus rowsum, grouped log: sum max(z,0) + log prod(1+e^-|z|)
#pragma unroll
        for (int rt = 0; rt < 4; rt++) {
#pragma unroll
            for (int r = 0; r < 4; r++) {
                const int row = (rtb + rt) * 16 + quad * 4 + r;
                float m = 0.f, Pp = 1.f;
#pragma unroll
                for (int ct = 0; ct < 4; ct++) {
                    const int col = col0 + ct * 16 + l16;
                    if (col < NSHORT) {
                        const float z = acc[rt][ct][r];
                        m += fmaxf(z, 0.f);
                        Pp *= 1.f + __expf(-fabsf(z));
                    }
                }
                float s = m + __logf(Pp);
                s = qreduce16(s);
                if (l16 == 0) part[(size_t)pslot * 256 + row] = s;
            }
        }
    } else {
        // sum_ct -log(1-r*sig(z)) = log prod(1+t) - log prod(1+t-r), t=e^-z
#pragma unroll
        for (int rt = 0; rt < 4; rt++) {
#pragma unroll
            for (int r = 0; r < 4; r++) {
                const int row = (rtb + rt) * 16 + quad * 4 + r;
                const float rv = sigf(rootlogit[row * 3 + ci]);
                float pd = 1.f, pn = 1.f;
#pragma unroll
                for (int ct = 0; ct < 4; ct++) {
                    const int col = col0 + ct * 16 + l16;
                    const float tv = fminf(__expf(-acc[rt][ct][r]), 1e6f);
                    const float d = (col < N) ? (1.f + tv) : 1.f;
                    const float n = (col < N) ? (1.f + tv - rv) : 1.f;
                    pd *= d; pn *= n;
                }
                float s = __logf(pd) - __logf(pn);
                s = qreduce16(s);
                if (l16 == 0) part[(size_t)pslot * 256 + row] = s;
            }
        }
    }
}

// head softplus (32, full-K) + w1 h (11, full-K) + roots (256) = 299 blocks
__global__ __launch_bounds__(256) void k_mm1(
    const float* __restrict__ x, const float* __restrict__ headW,
    const float* __restrict__ w10, const float* __restrict__ w11,
    const float* __restrict__ w12,
    float* __restrict__ phead,     // [32][256]
    float* h0, float* h1, float* h2,
    float* __restrict__ rootlogit)
{
    __shared__ __align__(16) short smem[16384];  // 32 KB: 2 x KC=4 chunks
    const int bx = blockIdx.x;
    if (bx < 32) {
        core_c<24, 4, 1, 1>(x, 0, headW, INF, NHEAD, bx, smem,
                            nullptr, 0, phead, bx, nullptr, 0);
    } else if (bx < 38) {
        core_c<24, 4, 0, 1>(x, 0, w10, INF, 384, bx - 32, smem,
                            h0, 384, nullptr, 0, nullptr, 0);
    } else if (bx < 41) {
        core_c<24, 4, 0, 1>(x, 0, w11, INF, 192, bx - 38, smem,
                            h1, 192, nullptr, 0, nullptr, 0);
    } else if (bx < 43) {
        core_c<24, 4, 0, 1>(x, 0, w12, INF, 96, bx - 41, smem,
                            h2, 96, nullptr, 0, nullptr, 0);
    } else {
        const int row = bx - 43, wave = threadIdx.x >> 6, lane = threadIdx.x & 63;
        if (wave < 3) {   // exact fp32 root logits
            const float* xr = x + row * INF;
            const float* wr = headW + (size_t)(NSHORT + wave) * INF;
            float s = 0.f;
            for (int k = lane; k < INF; k += 64) s += xr[k] * wr[k];
            s = wreduce64(s);
            if (lane == 0) rootlogit[row * 3 + wave] = s;
        }
    }
}

// LayerNorm+ReLU -> bf16 flat (f*) + fragment-permuted (p*); also zeroes out[0]
__global__ __launch_bounds__(256) void k_ln(const float* h0, const float* h1, const float* h2,
                                            const float* g0, const float* g1, const float* g2,
                                            const float* b0, const float* b1, const float* b2,
                                            __hip_bfloat16* f0, __hip_bfloat16* f1,
                                            __hip_bfloat16* f2,
                                            __hip_bfloat16* p0, __hip_bfloat16* p1,
                                            __hip_bfloat16* p2,
                                            float* __restrict__ out) {
    if (blockIdx.x == 0 && threadIdx.x == 0) out[0] = 0.f;
    const int task = blockIdx.x * 4 + (threadIdx.x >> 6);  // 0..767
    const int ci = task >> 8, row = task & 255, lane = threadIdx.x & 63;
    const float *h, *g, *bb; __hip_bfloat16 *fo, *po; int hsz, K32;
    if (ci == 0)      { h = h0; g = g0; bb = b0; fo = f0; po = p0; hsz = 384; K32 = 12; }
    else if (ci == 1) { h = h1; g = g1; bb = b1; fo = f1; po = p1; hsz = 192; K32 = 6; }
    else              { h = h2; g = g2; bb = b2; fo = f2; po = p2; hsz = 96;  K32 = 3; }
    const float* hr = h + (size_t)row * hsz;
    float s = 0.f, s2 = 0.f;
    for (int k = lane; k < hsz; k += 64) { const float v = hr[k]; s += v; s2 += v * v; }
    s = wreduce64(s); s2 = wreduce64(s2);
    const float mu = s / hsz;
    const float var = s2 / hsz - mu * mu;
    const float rsn = rsqrtf(var + 1e-5f);
    const int nch = hsz >> 3;
    if (lane < nch) {
        const f32x8 v = *(const f32x8*)(hr + lane * 8);
        const f32x8 gg = *(const f32x8*)(g + lane * 8);
        const f32x8 bv = *(const f32x8*)(bb + lane * 8);
        s16x8 o;
#pragma unroll
        for (int i = 0; i < 8; i++)
            o[i] = bfc(fmaxf((v[i] - mu) * rsn * gg[i] + bv[i], 0.f));
        *(s16x8*)((short*)fo + (size_t)row * hsz + lane * 8) = o;
        const size_t chunk = ((size_t)(row >> 4) * K32 + (lane >> 2)) * 64
                           + (lane & 3) * 16 + (row & 15);
        *(s16x8*)((short*)po + chunk * 8) = o;
    }
}

// BCE dense partials: 1533 stripes, chunked dbuf staging (R8-proven config)
__global__ __launch_bounds__(256, 4) void k_bce(const __hip_bfloat16* p0,
                                                const __hip_bfloat16* p1,
                                                const __hip_bfloat16* p2,
                                                const float* __restrict__ w20,
                                                const float* __restrict__ w21,
                                                const float* __restrict__ w22,
                                                float* __restrict__ part,
                                                const float* __restrict__ rootlogit) {
    __shared__ __align__(16) short smem[8192];  // 16 KB
    const int s = blockIdx.x;
    if (s < 157)
        core_c<12, 2, 2, 0>(p0, 0, w20, 384, 10000, s, smem,
                            nullptr, 0, part, s, rootlogit, 0);
    else if (s < 595)
        core_c<6, 2, 2, 0>(p1, 0, w21, 192, 28000, s - 157, smem,
                           nullptr, 0, part, s, rootlogit, 1);
    else
        core_c<3, 3, 2, 0>(p2, 0, w22, 96, 60000, s - 595, smem,
                           nullptr, 0, part, s, rootlogit, 2);
}

// per-row: target corrections + partial reduction + final mean
__global__ __launch_bounds__(256) void k_red(const float* __restrict__ part,
                                             const float* __restrict__ phead,
                                             const float* __restrict__ rootlogit,
                                             const int* __restrict__ target,
                                             const float* __restrict__ x,
                                             const float* __restrict__ headW,
                                             const __hip_bfloat16* f0,
                                             const __hip_bfloat16* f1,
                                             const __hip_bfloat16* f2,
                                             const float* w20, const float* w21, const float* w22,
                                             float* __restrict__ out) {
    const int row = blockIdx.x;
    const int t = threadIdx.x, wave = t >> 6, lane = t & 63;
    __shared__ float sx[INF];
    __shared__ __hip_bfloat16 shb[384 + 192 + 96];
    __shared__ int st[20];
    __shared__ float scorr[4];
    __shared__ float red[4][4];
    for (int i = t; i < INF; i += 256) sx[i] = x[row * INF + i];
    for (int i = t; i < 384; i += 256) shb[i] = f0[row * 384 + i];
    for (int i = t; i < 192; i += 256) shb[384 + i] = f1[row * 192 + i];
    for (int i = t; i < 96; i += 256)  shb[576 + i] = f2[row * 96 + i];
    if (t < 20) st[t] = target[row * 20 + t];
    if (t < 4) scorr[t] = 0.f;
    __syncthreads();
    for (int l = wave; l < 20; l += 4) {
        const int tg = st[l];
        bool dup = false;
        for (int m = 0; m < l; m++) dup |= (st[m] == tg);
        if (dup) continue;
        if (tg < NSHORT) {
            const float* wr = headW + (size_t)tg * INF;
            float z = 0.f;
            for (int k = lane; k < INF; k += 64) z += sx[k] * wr[k];
            z = wreduce64(z);
            if (lane == 0) atomicAdd(&scorr[3], -z);
        } else {
            int ci, low, hsz, hoff; const float* w2;
            if (tg < 12000)      { ci = 0; low = 2000;  hsz = 384; hoff = 0;   w2 = w20; }
            else if (tg < 40000) { ci = 1; low = 12000; hsz = 192; hoff = 384; w2 = w21; }
            else                 { ci = 2; low = 40000; hsz = 96;  hoff = 576; w2 = w22; }
            const float* wr = w2 + (size_t)(tg - low) * hsz;
            float z = 0.f;
            for (int k = lane; k < hsz; k += 64)
                z += __bfloat162float(shb[hoff + k]) * wr[k];
            z = wreduce64(z);
            if (lane == 0) {
                const float rvv = sigf(rootlogit[row * 3 + ci]);
                const float p = rvv * sigf(z);
                atomicAdd(&scorr[ci],
                          -fmaxf(__logf(p), -100.f) + fmaxf(__logf(1.f - p), -100.f));
            }
        }
    }
    // dense-partial + head-partial reduction
    float c0 = 0.f, c1 = 0.f, c2 = 0.f, hs = 0.f;
    for (int i = t; i < 1533; i += 256) {
        const float v = part[(size_t)i * 256 + row];
        if (i < 157) c0 += v; else if (i < 595) c1 += v; else c2 += v;
    }
    if (t < 32) hs = phead[(size_t)t * 256 + row];
    c0 = wreduce64(c0); c1 = wreduce64(c1); c2 = wreduce64(c2); hs = wreduce64(hs);
    if (lane == 0) { red[0][wave] = c0; red[1][wave] = c1; red[2][wave] = c2; red[3][wave] = hs; }
    __syncthreads();
    if (t == 0) {
        float cc[3];
        for (int i = 0; i < 3; i++) cc[i] = red[i][0] + red[i][1] + red[i][2] + red[i][3];
        float hsum = red[3][0] + red[3][1] + red[3][2] + red[3][3] + scorr[3];
        bool act[3] = {false, false, false};
        for (int l = 0; l < 20; l++) {
            const int tg = target[row * 20 + l];
            if (tg >= 2000) {
                if (tg < 12000) act[0] = true;
                else if (tg < 40000) act[1] = true;
                else act[2] = true;
            }
        }
        float total = 0.f, num = 2000.f;
        const float csz[3] = {10000.f, 28000.f, 60000.f};
        for (int i = 0; i < 3; i++) {
            if (act[i]) { total += cc[i] + scorr[i]; num += csz[i]; }
            else        { hsum += softplusf(rootlogit[row * 3 + i]); num += 1.f; }
        }
        atomicAdd(out, (hsum + total) / num * (1.f / 256.f));
    }
}

extern "C" void kernel_launch(void* const* d_in, const int* in_sizes, int n_in,
                              void* d_out, int out_size, void* d_ws, size_t ws_size,
                              hipStream_t stream) {
    const float* x      = (const float*)d_in[0];
    const float* headW  = (const float*)d_in[1];
    const int*   target = (const int*)d_in[2];
    const float* w10 = (const float*)d_in[3];
    const float* g0  = (const float*)d_in[4];
    const float* b0  = (const float*)d_in[5];
    const float* w20 = (const float*)d_in[6];
    const float* w11 = (const float*)d_in[7];
    const float* g1  = (const float*)d_in[8];
    const float* b1  = (const float*)d_in[9];
    const float* w21 = (const float*)d_in[10];
    const float* w12 = (const float*)d_in[11];
    const float* g2  = (const float*)d_in[12];
    const float* b2  = (const float*)d_in[13];
    const float* w22 = (const float*)d_in[14];
    float* out = (float*)d_out;

    char* ws = (char*)d_ws;
    size_t off = 0;
    auto carve = [&](size_t bytes) -> void* {
        void* p = ws + off;
        off += (bytes + 255) & ~(size_t)255;
        return p;
    };
    float* h0            = (float*)carve((size_t)256 * 384 * 4);
    float* h1            = (float*)carve((size_t)256 * 192 * 4);
    float* h2            = (float*)carve((size_t)256 * 96 * 4);
    __hip_bfloat16* f0   = (__hip_bfloat16*)carve((size_t)256 * 384 * 2);
    __hip_bfloat16* f1   = (__hip_bfloat16*)carve((size_t)256 * 192 * 2);
    __hip_bfloat16* f2   = (__hip_bfloat16*)carve((size_t)256 * 96 * 2);
    __hip_bfloat16* p0   = (__hip_bfloat16*)carve((size_t)256 * 384 * 2);
    __hip_bfloat16* p1   = (__hip_bfloat16*)carve((size_t)256 * 192 * 2);
    __hip_bfloat16* p2   = (__hip_bfloat16*)carve((size_t)256 * 96 * 2);
    float* rootlogit     = (float*)carve((size_t)256 * 3 * 4);
    float* phead         = (float*)carve((size_t)32 * 256 * 4);
    float* part          = (float*)carve((size_t)1536 * 256 * 4);

    k_mm1<<<299, 256, 0, stream>>>(x, headW, w10, w11, w12,
                                   phead, h0, h1, h2, rootlogit);
    k_ln<<<192, 256, 0, stream>>>(h0, h1, h2, g0, g1, g2, b0, b1, b2,
                                  f0, f1, f2, p0, p1, p2, out);
    k_bce<<<1533, 256, 0, stream>>>(p0, p1, p2, w20, w21, w22, part, rootlogit);
    k_red<<<256, 256, 0, stream>>>(part, phead, rootlogit, target, x, headW,
                                   f0, f1, f2, w20, w21, w22, out);

    (void)in_sizes; (void)n_in; (void)out_size; (void)ws_size;
}